// Round 4
// baseline (211.744 us; speedup 1.0000x reference)
//
#include <hip/hip_runtime.h>
#include <hip/hip_bf16.h>

#define S 512
#define KEEP 64
#define SPARSITY 0.125f
#define SLOPE 5.0f

// Geometry: example is [B=64, C=8, H=512, S=512] f32.
#define ROW4 128            // float4 per row (S/4)
#define ROWS_PER_BATCH 4096 // C*H
#define BLOCKS_PER_BATCH 32
#define ROWS_PER_BLOCK 128  // ROWS_PER_BATCH / BLOCKS_PER_BATCH
#define BATCH4 524288       // ROWS_PER_BATCH * ROW4

typedef float vf4 __attribute__((ext_vector_type(4)));

// One block per batch row b. 512 threads, one per frequency line s.
// Exact top-64 via rank counting (ties -> lowest index, matching lax.top_k).
__global__ __launch_bounds__(512) void loupe_mask_kernel(
    const float* __restrict__ weight,
    const float* __restrict__ thresh,
    float* __restrict__ mask) {
    __shared__ float red[S];
    __shared__ float sc[S];

    const int b = blockIdx.x;
    const int s = threadIdx.x;

    // Numerically-stable sigmoid, matching jax.nn.sigmoid.
    const float z = SLOPE * weight[s];
    const float e = expf(-fabsf(z));
    const float x = (z >= 0.0f) ? (1.0f / (1.0f + e)) : (e / (1.0f + e));

    red[s] = x;
    __syncthreads();
    #pragma unroll
    for (int off = S / 2; off > 0; off >>= 1) {
        if (s < off) red[s] += red[s + off];
        __syncthreads();
    }
    const float xbar = red[0] * (1.0f / (float)S);

    float pm;
    if (xbar > SPARSITY) {
        pm = x * SPARSITY / xbar;
    } else {
        pm = 1.0f - (1.0f - x) * (1.0f - SPARSITY) / (1.0f - xbar);
    }

    const float score = pm - thresh[b * S + s];
    sc[s] = score;
    __syncthreads();

    int rank = 0;
    #pragma unroll 8
    for (int j = 0; j < S; ++j) {
        const float o = sc[j];
        rank += (o > score) || (o == score && j < s);
    }
    mask[b * S + s] = (rank < KEEP) ? 1.0f : 0.0f;
}

// Streaming multiply, register-resident mask, software-pipelined:
// loads for group g+1 are issued BEFORE stores of group g, so the HBM
// read stream never idles behind the write bursts. All buffer indices
// are compile-time (full unroll, alternating named buffers).
#define LOAD4(EBUF, G)                                                   \
    {                                                                    \
        const vf4* p_ = src + (G) * 8 * ROW4;                            \
        EBUF[0] = __builtin_nontemporal_load(p_);                        \
        EBUF[1] = __builtin_nontemporal_load(p_ + 2 * ROW4);             \
        EBUF[2] = __builtin_nontemporal_load(p_ + 4 * ROW4);             \
        EBUF[3] = __builtin_nontemporal_load(p_ + 6 * ROW4);             \
    }
#define STORE4(EBUF, G)                                                  \
    {                                                                    \
        vf4* p_ = dst + (G) * 8 * ROW4;                                  \
        __builtin_nontemporal_store(EBUF[0] * m, p_);                    \
        __builtin_nontemporal_store(EBUF[1] * m, p_ + 2 * ROW4);         \
        __builtin_nontemporal_store(EBUF[2] * m, p_ + 4 * ROW4);         \
        __builtin_nontemporal_store(EBUF[3] * m, p_ + 6 * ROW4);         \
    }

__global__ __launch_bounds__(256) void loupe_apply_kernel(
    const vf4* __restrict__ ex,
    const vf4* __restrict__ mask4,   // [B][ROW4]
    vf4* __restrict__ out) {
    const int b     = blockIdx.x >> 5;          // / BLOCKS_PER_BATCH
    const int chunk = blockIdx.x & 31;
    const int t     = threadIdx.x;
    const int s4    = t & 127;
    const int rowo  = t >> 7;                    // 0 or 1

    const vf4 m = mask4[b * ROW4 + s4];          // loaded once, L2-hit

    const int base = b * BATCH4 + (chunk * ROWS_PER_BLOCK + rowo) * ROW4 + s4;
    const vf4* src = ex  + base;
    vf4*       dst = out + base;

    vf4 e0[4], e1[4];
    LOAD4(e0, 0);
    #pragma unroll
    for (int g = 0; g < 15; ++g) {
        if (g & 1) { LOAD4(e0, g + 1); STORE4(e1, g); }
        else       { LOAD4(e1, g + 1); STORE4(e0, g); }
    }
    STORE4(e1, 15);   // group 15 was loaded into e1 at g=14
}

extern "C" void kernel_launch(void* const* d_in, const int* in_sizes, int n_in,
                              void* d_out, int out_size, void* d_ws, size_t ws_size,
                              hipStream_t stream) {
    const float* example = (const float*)d_in[0];   // [64, 8, 512, 512]
    const float* weight  = (const float*)d_in[1];   // [512]
    const float* thresh  = (const float*)d_in[2];   // [64, 512]
    float* out  = (float*)d_out;
    float* mask = (float*)d_ws;                     // [64, 512] floats = 128 KB

    const int B = in_sizes[2] / S;                  // 64

    loupe_mask_kernel<<<B, S, 0, stream>>>(weight, thresh, mask);

    loupe_apply_kernel<<<B * BLOCKS_PER_BATCH, 256, 0, stream>>>(
        (const vf4*)example, (const vf4*)mask, (vf4*)out);
}